// Round 20
// baseline (88.659 us; speedup 1.0000x reference)
//
#include <hip/hip_runtime.h>
#include <math.h>

#define NV 6890
#define N3 20670       // NV*3
#define NJNT 24
#define NBETA 10
#define NPF 207
#define NJO 19
#define NBATCH 512
#define NJK 456        // NJO*NJNT
#define NJKP 512       // padded jk (GEMM N)
#define NCOEF 218      // [pf 207 | beta 10 | 1]
#define PROWSP 768     // padded P rows (GEMM M, 128-row tiles)
#define KPAD 6912      // 9 * 768
#define KSPLIT 9
#define KCH 768        // 12 * 64
#define CSTR 224       // pfc row stride
#define CSTRV 6912     // padded jrT/wT/jgT row stride (float4-safe)

// kA role boundaries
#define TR2 54         // LDS-tiled transpose: ceil(NV/128)
#define RODB 48        // rodrigues: NBATCH*NJNT/256
#define PMV 1479       // Pm value part: ceil(219*1728/256)
#define PMP 763        // Pm pad rows: ceil(113*1728/256)
// kB role boundaries
#define C4R 1728       // short4 per Cb row
#define CMB (NJKP * C4R / 256)   // 3456 kCm blocks
#define SJB 264        // SJ: 24*11
// redD4C role boundaries
#define RD4B 438       // 219*512/256
#define CHB 48         // chainP: NBATCH*NJNT/256
// D4: rows 0..217 = (D[3r],D[3r+1],D[3r+2],0); row 218 = (c0,0,0,0)
#define D4R 219
// k_S5b r-split
#define RSP 2
#define RCH 109        // 2*109 = 218 exactly
#define SSTRIDE ((size_t)NBATCH * 3 * NJK)   // one Spart slice

typedef __attribute__((ext_vector_type(8))) short bfx8;
typedef __attribute__((ext_vector_type(4))) float fx4;

#define LDSP(x) ((__attribute__((address_space(3))) void*)(x))
#define GLBP(x) ((const __attribute__((address_space(1))) void*)(x))

__constant__ int d_par[NJNT] = {0,0,0,0,1,2,3,4,5,6,7,8,9,9,9,12,13,14,16,17,18,19,20,21};
// ancestor path (root..j) per joint, -1 padded; max depth 9
__constant__ int d_path[NJNT][9] = {
  {0,-1,-1,-1,-1,-1,-1,-1,-1},
  {0,1,-1,-1,-1,-1,-1,-1,-1},
  {0,2,-1,-1,-1,-1,-1,-1,-1},
  {0,3,-1,-1,-1,-1,-1,-1,-1},
  {0,1,4,-1,-1,-1,-1,-1,-1},
  {0,2,5,-1,-1,-1,-1,-1,-1},
  {0,3,6,-1,-1,-1,-1,-1,-1},
  {0,1,4,7,-1,-1,-1,-1,-1},
  {0,2,5,8,-1,-1,-1,-1,-1},
  {0,3,6,9,-1,-1,-1,-1,-1},
  {0,1,4,7,10,-1,-1,-1,-1},
  {0,2,5,8,11,-1,-1,-1,-1},
  {0,3,6,9,12,-1,-1,-1,-1},
  {0,3,6,9,13,-1,-1,-1,-1},
  {0,3,6,9,14,-1,-1,-1,-1},
  {0,3,6,9,12,15,-1,-1,-1},
  {0,3,6,9,13,16,-1,-1,-1},
  {0,3,6,9,14,17,-1,-1,-1},
  {0,3,6,9,13,16,18,-1,-1},
  {0,3,6,9,14,17,19,-1,-1},
  {0,3,6,9,13,16,18,20,-1},
  {0,3,6,9,14,17,19,21,-1},
  {0,3,6,9,13,16,18,20,22},
  {0,3,6,9,14,17,19,21,23}};

__device__ inline short f2bf(float f) {
  union { float f; unsigned u; } x; x.f = f;
  unsigned r = (x.u + 0x7fffu + ((x.u >> 16) & 1u)) >> 16;
  return (short)r;
}

// ============ kA: transpose(jr,lbs,Jreg) || rodrigues(b,j) || Pm(vec) ============
// All roles consume only kernel INPUTS — no intra-dispatch dependencies.
__global__ void __launch_bounds__(256) kA(const float* __restrict__ jr,
                                          const float* __restrict__ lbs,
                                          const float* __restrict__ Jreg,
                                          const float* __restrict__ sdirs,
                                          const float* __restrict__ vtmpl,
                                          const float* __restrict__ theta,
                                          const float* __restrict__ beta,
                                          const float* __restrict__ pdirs,
                                          float* __restrict__ jrT, float* __restrict__ wT,
                                          float* __restrict__ jgT,
                                          float* __restrict__ Rs, float* __restrict__ pfc,
                                          short* __restrict__ Pb) {
  __shared__ float tj[128 * NJO];    // 9.5KB
  __shared__ float tw[128 * NJNT];   // 12KB
  __shared__ float tg[128 * NJNT];   // 12KB
  int bx = blockIdx.x, tid = threadIdx.x;
  if (bx < TR2) {
    // ---- transpose via LDS tile: coalesced reads AND writes ----
    int v0 = bx * 128;
    for (int i = tid; i < 128 * NJO; i += 256) {
      int g = v0 * NJO + i;
      tj[i] = (g < NV * NJO) ? jr[g] : 0.f;
    }
    for (int i = tid; i < 128 * NJNT; i += 256) {
      int g = v0 * NJNT + i;
      tw[i] = (g < NV * NJNT) ? lbs[g] : 0.f;
      tg[i] = (g < NV * NJNT) ? Jreg[g] : 0.f;
    }
    __syncthreads();
    for (int i = tid; i < 128 * (NJO + 2 * NJNT); i += 256) {
      int r = i >> 7, c = i & 127;
      int v = v0 + c;
      if (v >= NV) continue;
      if (r < NJO)            jrT[(size_t)r * CSTRV + v] = tj[c * NJO + r];
      else if (r < NJO + NJNT) wT[(size_t)(r - NJO) * CSTRV + v] = tw[c * NJNT + (r - NJO)];
      else                    jgT[(size_t)(r - NJO - NJNT) * CSTRV + v] = tg[c * NJNT + (r - NJO - NJNT)];
    }
  } else if (bx < TR2 + RODB) {
    int t2 = (bx - TR2) * 256 + tid;
    int b = t2 / NJNT, j = t2 - b * NJNT;
    float a0 = theta[b * 72 + j * 3 + 0];
    float a1 = theta[b * 72 + j * 3 + 1];
    float a2 = theta[b * 72 + j * 3 + 2];
    float e0 = a0 + 1e-8f, e1 = a1 + 1e-8f, e2 = a2 + 1e-8f;
    float ang = sqrtf(e0 * e0 + e1 * e1 + e2 * e2);
    float inv = 1.0f / ang;
    float h = 0.5f * ang;
    float w = cosf(h), s = sinf(h);
    float x = a0 * inv * s, y = a1 * inv * s, z = a2 * inv * s;
    float R[9];
    R[0] = w*w + x*x - y*y - z*z; R[1] = 2.f*(x*y - w*z); R[2] = 2.f*(x*z + w*y);
    R[3] = 2.f*(x*y + w*z); R[4] = w*w - x*x + y*y - z*z; R[5] = 2.f*(y*z - w*x);
    R[6] = 2.f*(x*z - w*y); R[7] = 2.f*(y*z + w*x); R[8] = w*w - x*x - y*y + z*z;
#pragma unroll
    for (int r = 0; r < 9; ++r) Rs[b * 216 + j * 9 + r] = R[r];
    if (j >= 1) {
#pragma unroll
      for (int r = 0; r < 9; ++r)
        pfc[b * CSTR + (j - 1) * 9 + r] = R[r] - ((r % 4 == 0) ? 1.0f : 0.0f);
    } else {
#pragma unroll
      for (int i = 0; i < NBETA; ++i) pfc[b * CSTR + NPF + i] = beta[b * NBETA + i];
      pfc[b * CSTR + NPF + NBETA] = 1.0f;
    }
  } else if (bx < TR2 + RODB + PMV) {
    // ---- Pm values: thread = (s, 4 vertices); float4 reads, short4 writes ----
    int idx = (bx - TR2 - RODB) * 256 + tid;
    if (idx >= 219 * C4R) return;
    int s = idx / C4R, c4 = idx - s * C4R;
    int v0 = c4 * 4;
    if (s == 218) {   // ones row 654
      short one = f2bf(1.0f);
      short4 o;
      o.x = (v0 + 0 < NV) ? one : (short)0;
      o.y = (v0 + 1 < NV) ? one : (short)0;
      o.z = (v0 + 2 < NV) ? one : (short)0;
      o.w = (v0 + 3 < NV) ? one : (short)0;
      *(short4*)(Pb + (size_t)654 * KPAD + v0) = o;
      return;
    }
    const float* src; int base;
    if (s < 207)      { src = pdirs + (size_t)s * N3;         base = 3 * s; }
    else if (s < 217) { src = sdirs + (size_t)(s - 207) * N3; base = 621 + 3 * (s - 207); }
    else              { src = vtmpl;                           base = 651; }
    float e[12];
    if (v0 + 4 <= NV) {
      float4 a = *(const float4*)(src + 3 * v0);
      float4 b = *(const float4*)(src + 3 * v0 + 4);
      float4 c = *(const float4*)(src + 3 * v0 + 8);
      e[0]=a.x; e[1]=a.y; e[2]=a.z; e[3]=a.w; e[4]=b.x; e[5]=b.y;
      e[6]=b.z; e[7]=b.w; e[8]=c.x; e[9]=c.y; e[10]=c.z; e[11]=c.w;
    } else {
#pragma unroll
      for (int i = 0; i < 12; ++i) {
        int f = 3 * v0 + i;
        e[i] = (f < N3) ? src[f] : 0.f;
      }
    }
#pragma unroll
    for (int q = 0; q < 3; ++q) {
      short4 o;
      o.x = f2bf(e[0 + q]); o.y = f2bf(e[3 + q]);
      o.z = f2bf(e[6 + q]); o.w = f2bf(e[9 + q]);
      *(short4*)(Pb + (size_t)(base + q) * KPAD + v0) = o;
    }
  } else {
    // ---- Pm pad rows 655..767: zero ----
    int idx = (bx - TR2 - RODB - PMV) * 256 + tid;
    if (idx >= 113 * C4R) return;
    int r = idx / C4R, c4 = idx - r * C4R;
    short4 z; z.x = z.y = z.z = z.w = (short)0;
    *(short4*)(Pb + (size_t)(655 + r) * KPAD + c4 * 4) = z;
  }
}

// ============ kB: kCm || SJ (SJ reads jgT from kA — cross-dispatch) ============
__global__ void __launch_bounds__(256) kB(const float* __restrict__ jrT,
                                          const float* __restrict__ wT,
                                          const float* __restrict__ jgT,
                                          const float* __restrict__ sdirs,
                                          const float* __restrict__ vtmpl,
                                          short* __restrict__ Cb,
                                          float* __restrict__ SJ) {
  __shared__ float red[4][3];
  int bx = blockIdx.x, tid = threadIdx.x;
  if (bx < CMB) {
    int idx = bx * 256 + tid;
    int jk = idx / C4R;
    int c4 = idx - jk * C4R;
    int v0 = c4 * 4;
    short4 o;
    if (jk < NJK) {
      int j = jk / NJNT, k = jk - j * NJNT;
      float4 a = *(const float4*)(jrT + (size_t)j * CSTRV + v0);
      float4 w = *(const float4*)(wT + (size_t)k * CSTRV + v0);
      o.x = (v0 + 0 < NV) ? f2bf(a.x * w.x) : (short)0;
      o.y = (v0 + 1 < NV) ? f2bf(a.y * w.y) : (short)0;
      o.z = (v0 + 2 < NV) ? f2bf(a.z * w.z) : (short)0;
      o.w = (v0 + 3 < NV) ? f2bf(a.w * w.w) : (short)0;
    } else {
      o.x = o.y = o.z = o.w = (short)0;
    }
    *(short4*)(Cb + (size_t)jk * KPAD + v0) = o;
  } else {
    // ---- SJ[k][j][c] = sum_v jgT[j][v]*src[v,c]; coalesced jgT reads ----
    int s = bx - CMB;
    int j = s % NJNT, k = s / NJNT;
    const float* src = (k < NBETA) ? (sdirs + (size_t)k * N3) : vtmpl;
    const float* jg = jgT + (size_t)j * CSTRV;
    float a0 = 0.f, a1 = 0.f, a2 = 0.f;
    for (int v = tid; v < NV; v += 256) {
      float w = jg[v];
      a0 += w * src[v * 3 + 0];
      a1 += w * src[v * 3 + 1];
      a2 += w * src[v * 3 + 2];
    }
    int lane = tid & 63, wid = tid >> 6;
#pragma unroll
    for (int s2 = 1; s2 < 64; s2 <<= 1) {
      a0 += __shfl_xor(a0, s2); a1 += __shfl_xor(a1, s2); a2 += __shfl_xor(a2, s2);
    }
    if (lane == 0) { red[wid][0] = a0; red[wid][1] = a1; red[wid][2] = a2; }
    __syncthreads();
    if (tid == 0) {
      float* o = SJ + (k * NJNT + j) * 3;
      o[0] = red[0][0] + red[1][0] + red[2][0] + red[3][0];
      o[1] = red[0][1] + red[1][1] + red[2][1] + red[3][1];
      o[2] = red[0][2] + red[1][2] + red[2][2] + red[3][2];
    }
  }
}

// ============ MFMA GEMM: 128(M)x64(N) tile, 16 MFMA/wave/K-step ============
__global__ void __launch_bounds__(256) k_gemm(const short* __restrict__ Pb,
                                              const short* __restrict__ Cb,
                                              float* __restrict__ Dpart) {
  int m0 = blockIdx.x * 128;  // 6
  int n0 = blockIdx.y * 64;   // 8
  int kb0 = blockIdx.z * KCH; // 9
  __shared__ __align__(16) short As[128 * 64];  // 16KB
  __shared__ __align__(16) short Bs[64 * 64];   // 8KB
  int t = threadIdx.x;
  int wid = t >> 6, lane = t & 63;
  int fgrp = lane >> 4;
  fx4 acc[2][4];
#pragma unroll
  for (int r2 = 0; r2 < 2; ++r2)
#pragma unroll
    for (int j = 0; j < 4; ++j)
#pragma unroll
      for (int r = 0; r < 4; ++r) acc[r2][j][r] = 0.f;

  int lrow = lane >> 3;
  int gsrc = (lane & 7) ^ lrow;
  const short* sA[4]; short* dA[4];
#pragma unroll
  for (int i = 0; i < 4; ++i) {
    int rb = wid * 8 + i * 32;
    sA[i] = Pb + (size_t)(m0 + rb + lrow) * KPAD + kb0 + gsrc * 8;
    dA[i] = As + rb * 64;
  }
  const short* sB[2]; short* dB[2];
#pragma unroll
  for (int i = 0; i < 2; ++i) {
    int rb = wid * 8 + i * 32;
    sB[i] = Cb + (size_t)(n0 + rb + lrow) * KPAD + kb0 + gsrc * 8;
    dB[i] = Bs + rb * 64;
  }

  for (int kk = 0; kk < KCH / 64; ++kk) {
#pragma unroll
    for (int i = 0; i < 4; ++i) {
      __builtin_amdgcn_global_load_lds(GLBP(sA[i]), LDSP(dA[i]), 16, 0, 0);
      sA[i] += 64;
    }
#pragma unroll
    for (int i = 0; i < 2; ++i) {
      __builtin_amdgcn_global_load_lds(GLBP(sB[i]), LDSP(dB[i]), 16, 0, 0);
      sB[i] += 64;
    }
    __syncthreads();
#pragma unroll
    for (int ks = 0; ks < 2; ++ks) {
      int ga = ks * 4 + fgrp;
#pragma unroll
      for (int r2 = 0; r2 < 2; ++r2) {
        int arow = wid * 32 + r2 * 16 + (lane & 15);
        bfx8 a = *(const bfx8*)(As + arow * 64 + (ga ^ (arow & 7)) * 8);
#pragma unroll
        for (int j = 0; j < 4; ++j) {
          int bcol = j * 16 + (lane & 15);
          bfx8 b = *(const bfx8*)(Bs + bcol * 64 + (ga ^ (bcol & 7)) * 8);
          acc[r2][j] = __builtin_amdgcn_mfma_f32_16x16x32_bf16(a, b, acc[r2][j], 0, 0, 0);
        }
      }
    }
    __syncthreads();
  }
  float* dz = Dpart + (size_t)blockIdx.z * PROWSP * NJKP;
#pragma unroll
  for (int r2 = 0; r2 < 2; ++r2) {
    float* dst = dz + (size_t)(m0 + wid * 32 + r2 * 16 + (lane >> 4) * 4) * NJKP
               + n0 + (lane & 15);
#pragma unroll
    for (int j = 0; j < 4; ++j)
#pragma unroll
      for (int r = 0; r < 4; ++r)
        dst[(size_t)r * NJKP + j * 16] = acc[r2][j][r];
  }
}

// ============ J from SJ/beta, in registers ============
__device__ inline void getJ(const float* __restrict__ SJ, const float* bb, int i,
                            float& o0, float& o1, float& o2) {
  int r = i * 3;
  float a0 = SJ[NBETA * 72 + r + 0];
  float a1 = SJ[NBETA * 72 + r + 1];
  float a2 = SJ[NBETA * 72 + r + 2];
#pragma unroll
  for (int k = 0; k < NBETA; ++k) {
    a0 += bb[k] * SJ[k * 72 + r + 0];
    a1 += bb[k] * SJ[k * 72 + r + 1];
    a2 += bb[k] * SJ[k * 72 + r + 2];
  }
  o0 = a0; o1 = a1; o2 = a2;
}

// ============ redD4C: K-split reduce + repack || chainP (consumes kA/kB outputs) ======
__global__ void __launch_bounds__(256) k_redD4C(const float* __restrict__ Dpart,
                                                const float* __restrict__ beta,
                                                const float* __restrict__ SJ,
                                                const float* __restrict__ Rs,
                                                float* __restrict__ D4,
                                                float* __restrict__ A) {
  int bx = blockIdx.x, tid = threadIdx.x;
  if (bx < RD4B) {
    int idx = bx * 256 + tid;   // exactly D4R*NJKP
    int r = idx / NJKP, jk = idx - r * NJKP;
    float4 o;
    if (r < NCOEF) {
      float s0 = 0.f, s1 = 0.f, s2 = 0.f;
#pragma unroll
      for (int z = 0; z < KSPLIT; ++z) {
        const float* dp = Dpart + (size_t)z * PROWSP * NJKP + jk;
        s0 += dp[(size_t)(3 * r + 0) * NJKP];
        s1 += dp[(size_t)(3 * r + 1) * NJKP];
        s2 += dp[(size_t)(3 * r + 2) * NJKP];
      }
      o = make_float4(s0, s1, s2, 0.f);
    } else {
      float s = 0.f;
#pragma unroll
      for (int z = 0; z < KSPLIT; ++z)
        s += Dpart[(size_t)z * PROWSP * NJKP + (size_t)654 * NJKP + jk];
      o = make_float4(s, 0.f, 0.f, 0.f);
    }
    ((float4*)D4)[idx] = o;
  } else {
    // ---- chainP: path-product chain with fused J; thread = (b, j) ----
    int idx = (bx - RD4B) * 256 + tid;   // exactly NBATCH*NJNT
    int b = idx / NJNT, j = idx - b * NJNT;
    const float* Rb = Rs + b * 216;
    float bb[NBETA];
#pragma unroll
    for (int k = 0; k < NBETA; ++k) bb[k] = beta[b * NBETA + k];
    float jp0, jp1, jp2;
    getJ(SJ, bb, 0, jp0, jp1, jp2);
    float T[12];
#pragma unroll
    for (int r = 0; r < 3; ++r) {
      T[r * 4 + 0] = Rb[r * 3 + 0];
      T[r * 4 + 1] = Rb[r * 3 + 1];
      T[r * 4 + 2] = Rb[r * 3 + 2];
    }
    T[3] = jp0; T[7] = jp1; T[11] = jp2;
    for (int d = 1; d < 9; ++d) {
      int i = d_path[j][d];
      if (i < 0) break;
      float ji0, ji1, ji2;
      getJ(SJ, bb, i, ji0, ji1, ji2);
      float t0 = ji0 - jp0, t1 = ji1 - jp1, t2 = ji2 - jp2;
      const float* R = Rb + i * 9;
      float R0 = R[0], R1 = R[1], R2 = R[2], R3 = R[3], R4 = R[4];
      float R5 = R[5], R6 = R[6], R7 = R[7], R8 = R[8];
#pragma unroll
      for (int r = 0; r < 3; ++r) {
        float a0 = T[r * 4 + 0], a1 = T[r * 4 + 1], a2 = T[r * 4 + 2];
        T[r * 4 + 0] = a0 * R0 + a1 * R3 + a2 * R6;
        T[r * 4 + 1] = a0 * R1 + a1 * R4 + a2 * R7;
        T[r * 4 + 2] = a0 * R2 + a1 * R5 + a2 * R8;
        T[r * 4 + 3] = a0 * t0 + a1 * t1 + a2 * t2 + T[r * 4 + 3];
      }
      jp0 = ji0; jp1 = ji1; jp2 = ji2;
    }
    float* Ab = A + b * 288 + j * 12;
#pragma unroll
    for (int r = 0; r < 3; ++r) {
      float o0 = T[r * 4 + 0], o1 = T[r * 4 + 1], o2 = T[r * 4 + 2];
      Ab[r * 4 + 0] = o0;
      Ab[r * 4 + 1] = o1;
      Ab[r * 4 + 2] = o2;
      Ab[r * 4 + 3] = T[r * 4 + 3] - (o0 * jp0 + o1 * jp1 + o2 * jp2);
    }
  }
}

// ============ k_S5b: r-split; ONE float4 load per r-iter (packed D4) ============
__global__ void __launch_bounds__(256) k_S5b(const float* __restrict__ D4,
                                             const float* __restrict__ pfc,
                                             float* __restrict__ Spart) {
  int n0 = blockIdx.x * 64;
  int b0 = blockIdx.y * 8;
  int r0 = blockIdx.z * RCH;
  int r1 = r0 + RCH; if (r1 > NCOEF) r1 = NCOEF;
  int tid = threadIdx.x;
  int jk = tid & 63;
  int bg = (tid >> 6) * 2;          // wave-uniform
  const float4* D4v = (const float4*)D4;
  int jkg = n0 + jk;
  const float* c0p = pfc + (size_t)(b0 + bg + 0) * CSTR;  // wave-uniform base
  const float* c1p = pfc + (size_t)(b0 + bg + 1) * CSTR;
  float a00 = 0.f, a01 = 0.f, a02 = 0.f, a10 = 0.f, a11 = 0.f, a12 = 0.f;
#pragma unroll 4
  for (int r = r0; r < r1; ++r) {
    float4 d = D4v[(size_t)r * NJKP + jkg];
    float c0 = c0p[r];               // s_load (uniform)
    float c1 = c1p[r];
    a00 += c0 * d.x; a01 += c0 * d.y; a02 += c0 * d.z;
    a10 += c1 * d.x; a11 += c1 * d.y; a12 += c1 * d.z;
  }
  if (jkg < NJK) {
    float* base = Spart + (size_t)blockIdx.z * SSTRIDE;
    float* o0 = base + ((size_t)(b0 + bg + 0) * 3) * NJK + jkg;
    float* o1 = base + ((size_t)(b0 + bg + 1) * 3) * NJK + jkg;
    o0[0 * NJK] = a00; o0[1 * NJK] = a01; o0[2 * NJK] = a02;
    o1[0 * NJK] = a10; o1[1 * NJK] = a11; o1[2 * NJK] = a12;
  }
}

// ============ k_final3: LDS-staged epilogue; 2 batches/block, all-coalesced ============
__global__ void __launch_bounds__(128) k_final3(const float* __restrict__ Spart,
                                                const float* __restrict__ D4,
                                                const float* __restrict__ A,
                                                float* __restrict__ out) {
  __shared__ float S_ls[2 * 3 * NJK];   // 10.9KB
  __shared__ float A_ls[2 * 288];       // 2.3KB
  __shared__ float c0_ls[NJK];          // 1.8KB
  int blk = blockIdx.x, tid = threadIdx.x;
  int b0 = blk * 2;
  size_t sbase = (size_t)(b0 * 3) * NJK;
  for (int i = tid; i < 2 * 3 * NJK; i += 128)
    S_ls[i] = Spart[sbase + i] + Spart[SSTRIDE + sbase + i];
  for (int i = tid; i < 2 * 288; i += 128)
    A_ls[i] = A[(size_t)b0 * 288 + i];
  for (int i = tid; i < NJK; i += 128)
    c0_ls[i] = D4[((size_t)NCOEF * NJKP + i) * 4];
  __syncthreads();
  if (tid >= 2 * NJO * 3) return;
  int bq = tid / 57, r = tid - bq * 57;
  int j = r / 3, c = r - j * 3;
  const float* S0 = S_ls + (bq * 3 + 0) * NJK + j * NJNT;
  const float* S1 = S_ls + (bq * 3 + 1) * NJK + j * NJNT;
  const float* S2 = S_ls + (bq * 3 + 2) * NJK + j * NJNT;
  const float* Ab = A_ls + bq * 288;
  const float* cc = c0_ls + j * NJNT;
  float acc = 0.f;
#pragma unroll 4
  for (int k = 0; k < NJNT; ++k) {
    const float* Ar = Ab + k * 12 + c * 4;
    acc += Ar[0] * S0[k] + Ar[1] * S1[k] + Ar[2] * S2[k] + Ar[3] * cc[k];
  }
  out[(size_t)(b0 + bq) * 57 + r] = acc;
}

extern "C" void kernel_launch(void* const* d_in, const int* in_sizes, int n_in,
                              void* d_out, int out_size, void* d_ws, size_t ws_size,
                              hipStream_t stream) {
  const float* beta  = (const float*)d_in[0];
  const float* theta = (const float*)d_in[1];
  const float* vtmpl = (const float*)d_in[2];
  const float* sdirs = (const float*)d_in[3];
  const float* Jreg  = (const float*)d_in[4];
  const float* pdirs = (const float*)d_in[5];
  const float* lbs   = (const float*)d_in[6];
  const float* jreg2 = (const float*)d_in[7];
  float* out = (float*)d_out;

  float* ws    = (float*)d_ws;
  short* Cb    = (short*)ws;                              // 512*6912 bf16
  short* Pb    = Cb + (size_t)NJKP * KPAD;                // 768*6912 bf16
  float* Dpart = (float*)(Pb + (size_t)PROWSP * KPAD);    // 9*768*512 f32
  float* D4    = Dpart + (size_t)KSPLIT * PROWSP * NJKP;  // 219*512*4
  float* Spart = D4    + (size_t)D4R * NJKP * 4;          // 2*512*3*456
  float* pfc   = Spart + (size_t)RSP * SSTRIDE;           // 512*224
  float* Rs    = pfc   + (size_t)NBATCH * CSTR;           // 512*216
  float* A     = Rs    + (size_t)NBATCH * 216;            // 512*288
  float* jrT   = A     + (size_t)NBATCH * 288;            // 19*6912 (padded)
  float* wT    = jrT   + (size_t)NJO * CSTRV;             // 24*6912 (padded)
  float* jgT   = wT    + (size_t)NJNT * CSTRV;            // 24*6912 (padded)
  float* SJ    = jgT   + (size_t)NJNT * CSTRV;            // 11*72

  kA<<<dim3(TR2 + RODB + PMV + PMP), 256, 0, stream>>>(
      jreg2, lbs, Jreg, sdirs, vtmpl, theta, beta, pdirs,
      jrT, wT, jgT, Rs, pfc, Pb);
  kB<<<dim3(CMB + SJB), 256, 0, stream>>>(jrT, wT, jgT, sdirs, vtmpl, Cb, SJ);
  k_gemm<<<dim3(PROWSP / 128, NJKP / 64, KSPLIT), 256, 0, stream>>>(Pb, Cb, Dpart);
  k_redD4C<<<dim3(RD4B + CHB), 256, 0, stream>>>(Dpart, beta, SJ, Rs, D4, A);
  k_S5b<<<dim3(NJKP / 64, NBATCH / 8, RSP), 256, 0, stream>>>(D4, pfc, Spart);
  k_final3<<<dim3(NBATCH / 2), 128, 0, stream>>>(Spart, D4, A, out);
}

// Round 21
// 79.865 us; speedup vs baseline: 1.1101x; 1.1101x over previous
//
#include <hip/hip_runtime.h>
#include <math.h>

#define NV 6890
#define N3 20670       // NV*3
#define NJNT 24
#define NBETA 10
#define NPF 207
#define NJO 19
#define NBATCH 512
#define NJK 456        // NJO*NJNT
#define NJKP 512       // padded jk (GEMM N)
#define NCOEF 218      // [pf 207 | beta 10 | 1]
#define PROWSP 768     // padded P rows (GEMM M, 128-row tiles)
#define KPAD 6912      // 12 * 576
#define KSPLIT 12
#define KCH 576        // 9 * 64
#define CSTR 224       // pfc row stride
#define CSTRV 6912     // padded jrT/wT row stride (float4-safe)

// kA role boundaries
#define TR2 54         // LDS-tiled transpose: ceil(NV/128)
#define RODB 48        // rodrigues: NBATCH*NJNT/256
#define SJB 264        // SJ: 24*11
#define C4R 1728       // short4 per row
#define PMV 1479       // Pm value part: ceil(219*1728/256)
#define PMP 763        // Pm pad rows: ceil(113*1728/256)
// kB role boundaries
#define CHB 48         // chainP: NBATCH*NJNT/256
#define CMB (NJKP * C4R / 256)   // 3456 kCm blocks
// D4: rows 0..217 = (D[3r],D[3r+1],D[3r+2],0); row 218 = (c0,0,0,0)
#define D4R 219
// k_S5b r-split
#define RSP 2
#define RCH 109        // 2*109 = 218 exactly
#define SSTRIDE ((size_t)NBATCH * 3 * NJK)   // one Spart slice

typedef __attribute__((ext_vector_type(8))) short bfx8;
typedef __attribute__((ext_vector_type(4))) float fx4;

#define LDSP(x) ((__attribute__((address_space(3))) void*)(x))
#define GLBP(x) ((const __attribute__((address_space(1))) void*)(x))

__constant__ int d_par[NJNT] = {0,0,0,0,1,2,3,4,5,6,7,8,9,9,9,12,13,14,16,17,18,19,20,21};
// ancestor path (root..j) per joint, -1 padded; max depth 9
__constant__ int d_path[NJNT][9] = {
  {0,-1,-1,-1,-1,-1,-1,-1,-1},
  {0,1,-1,-1,-1,-1,-1,-1,-1},
  {0,2,-1,-1,-1,-1,-1,-1,-1},
  {0,3,-1,-1,-1,-1,-1,-1,-1},
  {0,1,4,-1,-1,-1,-1,-1,-1},
  {0,2,5,-1,-1,-1,-1,-1,-1},
  {0,3,6,-1,-1,-1,-1,-1,-1},
  {0,1,4,7,-1,-1,-1,-1,-1},
  {0,2,5,8,-1,-1,-1,-1,-1},
  {0,3,6,9,-1,-1,-1,-1,-1},
  {0,1,4,7,10,-1,-1,-1,-1},
  {0,2,5,8,11,-1,-1,-1,-1},
  {0,3,6,9,12,-1,-1,-1,-1},
  {0,3,6,9,13,-1,-1,-1,-1},
  {0,3,6,9,14,-1,-1,-1,-1},
  {0,3,6,9,12,15,-1,-1,-1},
  {0,3,6,9,13,16,-1,-1,-1},
  {0,3,6,9,14,17,-1,-1,-1},
  {0,3,6,9,13,16,18,-1,-1},
  {0,3,6,9,14,17,19,-1,-1},
  {0,3,6,9,13,16,18,20,-1},
  {0,3,6,9,14,17,19,21,-1},
  {0,3,6,9,13,16,18,20,22},
  {0,3,6,9,14,17,19,21,23}};

__device__ inline short f2bf(float f) {
  union { float f; unsigned u; } x; x.f = f;
  unsigned r = (x.u + 0x7fffu + ((x.u >> 16) & 1u)) >> 16;
  return (short)r;
}

// ============ kA: LDS-tiled transpose || rodrigues(b,j) || SJ || Pm(vec) ============
// All roles consume only kernel INPUTS — no intra-dispatch dependencies.
// SJ's latency-bound blocks are deliberately co-scheduled with Pm's streaming
// blocks (R20 lesson: SJ alone in a dispatch becomes an exposed tail).
__global__ void __launch_bounds__(256) kA(const float* __restrict__ jr,
                                          const float* __restrict__ lbs,
                                          const float* __restrict__ Jreg,
                                          const float* __restrict__ sdirs,
                                          const float* __restrict__ vtmpl,
                                          const float* __restrict__ theta,
                                          const float* __restrict__ beta,
                                          const float* __restrict__ pdirs,
                                          float* __restrict__ jrT, float* __restrict__ wT,
                                          float* __restrict__ SJ, float* __restrict__ Rs,
                                          float* __restrict__ pfc,
                                          short* __restrict__ Pb) {
  __shared__ float red[4][3];
  __shared__ float tj[128 * NJO];    // 9.5KB
  __shared__ float tw[128 * NJNT];   // 12KB
  int bx = blockIdx.x, tid = threadIdx.x;
  if (bx < TR2) {
    // ---- transpose via LDS tile: coalesced reads AND writes ----
    int v0 = bx * 128;
    for (int i = tid; i < 128 * NJO; i += 256) {
      int g = v0 * NJO + i;
      tj[i] = (g < NV * NJO) ? jr[g] : 0.f;
    }
    for (int i = tid; i < 128 * NJNT; i += 256) {
      int g = v0 * NJNT + i;
      tw[i] = (g < NV * NJNT) ? lbs[g] : 0.f;
    }
    __syncthreads();
    for (int i = tid; i < 128 * (NJO + NJNT); i += 256) {
      int r = i >> 7, c = i & 127;
      int v = v0 + c;
      if (v >= NV) continue;
      if (r < NJO) jrT[(size_t)r * CSTRV + v] = tj[c * NJO + r];
      else         wT[(size_t)(r - NJO) * CSTRV + v] = tw[c * NJNT + (r - NJO)];
    }
  } else if (bx < TR2 + RODB) {
    int t2 = (bx - TR2) * 256 + tid;
    int b = t2 / NJNT, j = t2 - b * NJNT;
    float a0 = theta[b * 72 + j * 3 + 0];
    float a1 = theta[b * 72 + j * 3 + 1];
    float a2 = theta[b * 72 + j * 3 + 2];
    float e0 = a0 + 1e-8f, e1 = a1 + 1e-8f, e2 = a2 + 1e-8f;
    float ang = sqrtf(e0 * e0 + e1 * e1 + e2 * e2);
    float inv = 1.0f / ang;
    float h = 0.5f * ang;
    float w = cosf(h), s = sinf(h);
    float x = a0 * inv * s, y = a1 * inv * s, z = a2 * inv * s;
    float R[9];
    R[0] = w*w + x*x - y*y - z*z; R[1] = 2.f*(x*y - w*z); R[2] = 2.f*(x*z + w*y);
    R[3] = 2.f*(x*y + w*z); R[4] = w*w - x*x + y*y - z*z; R[5] = 2.f*(y*z - w*x);
    R[6] = 2.f*(x*z - w*y); R[7] = 2.f*(y*z + w*x); R[8] = w*w - x*x - y*y + z*z;
#pragma unroll
    for (int r = 0; r < 9; ++r) Rs[b * 216 + j * 9 + r] = R[r];
    if (j >= 1) {
#pragma unroll
      for (int r = 0; r < 9; ++r)
        pfc[b * CSTR + (j - 1) * 9 + r] = R[r] - ((r % 4 == 0) ? 1.0f : 0.0f);
    } else {
#pragma unroll
      for (int i = 0; i < NBETA; ++i) pfc[b * CSTR + NPF + i] = beta[b * NBETA + i];
      pfc[b * CSTR + NPF + NBETA] = 1.0f;
    }
  } else if (bx < TR2 + RODB + SJB) {
    int s = bx - TR2 - RODB;
    int j = s % NJNT, k = s / NJNT;
    const float* src = (k < NBETA) ? (sdirs + (size_t)k * N3) : vtmpl;
    float a0 = 0.f, a1 = 0.f, a2 = 0.f;
    for (int v = tid; v < NV; v += 256) {
      float w = Jreg[v * NJNT + j];
      a0 += w * src[v * 3 + 0];
      a1 += w * src[v * 3 + 1];
      a2 += w * src[v * 3 + 2];
    }
    int lane = tid & 63, wid = tid >> 6;
#pragma unroll
    for (int s2 = 1; s2 < 64; s2 <<= 1) {
      a0 += __shfl_xor(a0, s2); a1 += __shfl_xor(a1, s2); a2 += __shfl_xor(a2, s2);
    }
    if (lane == 0) { red[wid][0] = a0; red[wid][1] = a1; red[wid][2] = a2; }
    __syncthreads();
    if (tid == 0) {
      float* o = SJ + (k * NJNT + j) * 3;
      o[0] = red[0][0] + red[1][0] + red[2][0] + red[3][0];
      o[1] = red[0][1] + red[1][1] + red[2][1] + red[3][1];
      o[2] = red[0][2] + red[1][2] + red[2][2] + red[3][2];
    }
  } else if (bx < TR2 + RODB + SJB + PMV) {
    // ---- Pm values: thread = (s, 4 vertices); float4 reads, short4 writes ----
    int idx = (bx - TR2 - RODB - SJB) * 256 + tid;
    if (idx >= 219 * C4R) return;
    int s = idx / C4R, c4 = idx - s * C4R;
    int v0 = c4 * 4;
    if (s == 218) {   // ones row 654
      short one = f2bf(1.0f);
      short4 o;
      o.x = (v0 + 0 < NV) ? one : (short)0;
      o.y = (v0 + 1 < NV) ? one : (short)0;
      o.z = (v0 + 2 < NV) ? one : (short)0;
      o.w = (v0 + 3 < NV) ? one : (short)0;
      *(short4*)(Pb + (size_t)654 * KPAD + v0) = o;
      return;
    }
    const float* src; int base;
    if (s < 207)      { src = pdirs + (size_t)s * N3;         base = 3 * s; }
    else if (s < 217) { src = sdirs + (size_t)(s - 207) * N3; base = 621 + 3 * (s - 207); }
    else              { src = vtmpl;                           base = 651; }
    float e[12];
    if (v0 + 4 <= NV) {
      float4 a = *(const float4*)(src + 3 * v0);
      float4 b = *(const float4*)(src + 3 * v0 + 4);
      float4 c = *(const float4*)(src + 3 * v0 + 8);
      e[0]=a.x; e[1]=a.y; e[2]=a.z; e[3]=a.w; e[4]=b.x; e[5]=b.y;
      e[6]=b.z; e[7]=b.w; e[8]=c.x; e[9]=c.y; e[10]=c.z; e[11]=c.w;
    } else {
#pragma unroll
      for (int i = 0; i < 12; ++i) {
        int f = 3 * v0 + i;
        e[i] = (f < N3) ? src[f] : 0.f;
      }
    }
#pragma unroll
    for (int q = 0; q < 3; ++q) {
      short4 o;
      o.x = f2bf(e[0 + q]); o.y = f2bf(e[3 + q]);
      o.z = f2bf(e[6 + q]); o.w = f2bf(e[9 + q]);
      *(short4*)(Pb + (size_t)(base + q) * KPAD + v0) = o;
    }
  } else {
    // ---- Pm pad rows 655..767: zero ----
    int idx = (bx - TR2 - RODB - SJB - PMV) * 256 + tid;
    if (idx >= 113 * C4R) return;
    int r = idx / C4R, c4 = idx - r * C4R;
    short4 z; z.x = z.y = z.z = z.w = (short)0;
    *(short4*)(Pb + (size_t)(655 + r) * KPAD + c4 * 4) = z;
  }
}

// ============ J from SJ/beta, in registers ============
__device__ inline void getJ(const float* __restrict__ SJ, const float* bb, int i,
                            float& o0, float& o1, float& o2) {
  int r = i * 3;
  float a0 = SJ[NBETA * 72 + r + 0];
  float a1 = SJ[NBETA * 72 + r + 1];
  float a2 = SJ[NBETA * 72 + r + 2];
#pragma unroll
  for (int k = 0; k < NBETA; ++k) {
    a0 += bb[k] * SJ[k * 72 + r + 0];
    a1 += bb[k] * SJ[k * 72 + r + 1];
    a2 += bb[k] * SJ[k * 72 + r + 2];
  }
  o0 = a0; o1 = a1; o2 = a2;
}

// ============ kB: chainP || kCm — both consume only kA outputs ============
__global__ void __launch_bounds__(256) kB(const float* __restrict__ beta,
                                          const float* __restrict__ SJ,
                                          const float* __restrict__ Rs,
                                          const float* __restrict__ jrT,
                                          const float* __restrict__ wT,
                                          float* __restrict__ A,
                                          short* __restrict__ Cb) {
  int bx = blockIdx.x, tid = threadIdx.x;
  if (bx < CHB) {
    int idx = bx * 256 + tid;          // exactly NBATCH*NJNT
    int b = idx / NJNT, j = idx - b * NJNT;
    const float* Rb = Rs + b * 216;
    float bb[NBETA];
#pragma unroll
    for (int k = 0; k < NBETA; ++k) bb[k] = beta[b * NBETA + k];
    float jp0, jp1, jp2;
    getJ(SJ, bb, 0, jp0, jp1, jp2);
    float T[12];
#pragma unroll
    for (int r = 0; r < 3; ++r) {
      T[r * 4 + 0] = Rb[r * 3 + 0];
      T[r * 4 + 1] = Rb[r * 3 + 1];
      T[r * 4 + 2] = Rb[r * 3 + 2];
    }
    T[3] = jp0; T[7] = jp1; T[11] = jp2;
    for (int d = 1; d < 9; ++d) {
      int i = d_path[j][d];
      if (i < 0) break;
      float ji0, ji1, ji2;
      getJ(SJ, bb, i, ji0, ji1, ji2);
      float t0 = ji0 - jp0, t1 = ji1 - jp1, t2 = ji2 - jp2;
      const float* R = Rb + i * 9;
      float R0 = R[0], R1 = R[1], R2 = R[2], R3 = R[3], R4 = R[4];
      float R5 = R[5], R6 = R[6], R7 = R[7], R8 = R[8];
#pragma unroll
      for (int r = 0; r < 3; ++r) {
        float a0 = T[r * 4 + 0], a1 = T[r * 4 + 1], a2 = T[r * 4 + 2];
        T[r * 4 + 0] = a0 * R0 + a1 * R3 + a2 * R6;
        T[r * 4 + 1] = a0 * R1 + a1 * R4 + a2 * R7;
        T[r * 4 + 2] = a0 * R2 + a1 * R5 + a2 * R8;
        T[r * 4 + 3] = a0 * t0 + a1 * t1 + a2 * t2 + T[r * 4 + 3];
      }
      jp0 = ji0; jp1 = ji1; jp2 = ji2;
    }
    float* Ab = A + b * 288 + j * 12;
#pragma unroll
    for (int r = 0; r < 3; ++r) {
      float o0 = T[r * 4 + 0], o1 = T[r * 4 + 1], o2 = T[r * 4 + 2];
      Ab[r * 4 + 0] = o0;
      Ab[r * 4 + 1] = o1;
      Ab[r * 4 + 2] = o2;
      Ab[r * 4 + 3] = T[r * 4 + 3] - (o0 * jp0 + o1 * jp1 + o2 * jp2);
    }
  } else {
    int idx = (bx - CHB) * 256 + tid;
    int jk = idx / C4R;
    int c4 = idx - jk * C4R;
    int v0 = c4 * 4;
    short4 o;
    if (jk < NJK) {
      int j = jk / NJNT, k = jk - j * NJNT;
      float4 a = *(const float4*)(jrT + (size_t)j * CSTRV + v0);
      float4 w = *(const float4*)(wT + (size_t)k * CSTRV + v0);
      o.x = (v0 + 0 < NV) ? f2bf(a.x * w.x) : (short)0;
      o.y = (v0 + 1 < NV) ? f2bf(a.y * w.y) : (short)0;
      o.z = (v0 + 2 < NV) ? f2bf(a.z * w.z) : (short)0;
      o.w = (v0 + 3 < NV) ? f2bf(a.w * w.w) : (short)0;
    } else {
      o.x = o.y = o.z = o.w = (short)0;
    }
    *(short4*)(Cb + (size_t)jk * KPAD + v0) = o;
  }
}

// ============ MFMA GEMM: 128(M)x64(N) tile, 16 MFMA/wave/K-step ============
__global__ void __launch_bounds__(256) k_gemm(const short* __restrict__ Pb,
                                              const short* __restrict__ Cb,
                                              float* __restrict__ Dpart) {
  int m0 = blockIdx.x * 128;  // 6
  int n0 = blockIdx.y * 64;   // 8
  int kb0 = blockIdx.z * KCH; // 12
  __shared__ __align__(16) short As[128 * 64];  // 16KB
  __shared__ __align__(16) short Bs[64 * 64];   // 8KB
  int t = threadIdx.x;
  int wid = t >> 6, lane = t & 63;
  int fgrp = lane >> 4;
  fx4 acc[2][4];
#pragma unroll
  for (int r2 = 0; r2 < 2; ++r2)
#pragma unroll
    for (int j = 0; j < 4; ++j)
#pragma unroll
      for (int r = 0; r < 4; ++r) acc[r2][j][r] = 0.f;

  int lrow = lane >> 3;
  int gsrc = (lane & 7) ^ lrow;
  const short* sA[4]; short* dA[4];
#pragma unroll
  for (int i = 0; i < 4; ++i) {
    int rb = wid * 8 + i * 32;
    sA[i] = Pb + (size_t)(m0 + rb + lrow) * KPAD + kb0 + gsrc * 8;
    dA[i] = As + rb * 64;
  }
  const short* sB[2]; short* dB[2];
#pragma unroll
  for (int i = 0; i < 2; ++i) {
    int rb = wid * 8 + i * 32;
    sB[i] = Cb + (size_t)(n0 + rb + lrow) * KPAD + kb0 + gsrc * 8;
    dB[i] = Bs + rb * 64;
  }

  for (int kk = 0; kk < KCH / 64; ++kk) {
#pragma unroll
    for (int i = 0; i < 4; ++i) {
      __builtin_amdgcn_global_load_lds(GLBP(sA[i]), LDSP(dA[i]), 16, 0, 0);
      sA[i] += 64;
    }
#pragma unroll
    for (int i = 0; i < 2; ++i) {
      __builtin_amdgcn_global_load_lds(GLBP(sB[i]), LDSP(dB[i]), 16, 0, 0);
      sB[i] += 64;
    }
    __syncthreads();
#pragma unroll
    for (int ks = 0; ks < 2; ++ks) {
      int ga = ks * 4 + fgrp;
#pragma unroll
      for (int r2 = 0; r2 < 2; ++r2) {
        int arow = wid * 32 + r2 * 16 + (lane & 15);
        bfx8 a = *(const bfx8*)(As + arow * 64 + (ga ^ (arow & 7)) * 8);
#pragma unroll
        for (int j = 0; j < 4; ++j) {
          int bcol = j * 16 + (lane & 15);
          bfx8 b = *(const bfx8*)(Bs + bcol * 64 + (ga ^ (bcol & 7)) * 8);
          acc[r2][j] = __builtin_amdgcn_mfma_f32_16x16x32_bf16(a, b, acc[r2][j], 0, 0, 0);
        }
      }
    }
    __syncthreads();
  }
  float* dz = Dpart + (size_t)blockIdx.z * PROWSP * NJKP;
#pragma unroll
  for (int r2 = 0; r2 < 2; ++r2) {
    float* dst = dz + (size_t)(m0 + wid * 32 + r2 * 16 + (lane >> 4) * 4) * NJKP
               + n0 + (lane & 15);
#pragma unroll
    for (int j = 0; j < 4; ++j)
#pragma unroll
      for (int r = 0; r < 4; ++r)
        dst[(size_t)r * NJKP + j * 16] = acc[r2][j][r];
  }
}

// ============ k_redD4: K-split reduce + repack for S5b ============
__global__ void k_redD4(const float* __restrict__ Dpart, float* __restrict__ D4) {
  int idx = blockIdx.x * 256 + threadIdx.x;   // D4R*NJKP = 112128
  if (idx >= D4R * NJKP) return;
  int r = idx / NJKP, jk = idx - r * NJKP;
  float4 o;
  if (r < NCOEF) {
    float s0 = 0.f, s1 = 0.f, s2 = 0.f;
#pragma unroll
    for (int z = 0; z < KSPLIT; ++z) {
      const float* dp = Dpart + (size_t)z * PROWSP * NJKP + jk;
      s0 += dp[(size_t)(3 * r + 0) * NJKP];
      s1 += dp[(size_t)(3 * r + 1) * NJKP];
      s2 += dp[(size_t)(3 * r + 2) * NJKP];
    }
    o = make_float4(s0, s1, s2, 0.f);
  } else {
    float s = 0.f;
#pragma unroll
    for (int z = 0; z < KSPLIT; ++z)
      s += Dpart[(size_t)z * PROWSP * NJKP + (size_t)654 * NJKP + jk];
    o = make_float4(s, 0.f, 0.f, 0.f);
  }
  ((float4*)D4)[idx] = o;
}

// ============ k_S5b: r-split; ONE float4 load per r-iter (packed D4) ============
__global__ void __launch_bounds__(256) k_S5b(const float* __restrict__ D4,
                                             const float* __restrict__ pfc,
                                             float* __restrict__ Spart) {
  int n0 = blockIdx.x * 64;
  int b0 = blockIdx.y * 8;
  int r0 = blockIdx.z * RCH;
  int r1 = r0 + RCH; if (r1 > NCOEF) r1 = NCOEF;
  int tid = threadIdx.x;
  int jk = tid & 63;
  int bg = (tid >> 6) * 2;          // wave-uniform
  const float4* D4v = (const float4*)D4;
  int jkg = n0 + jk;
  const float* c0p = pfc + (size_t)(b0 + bg + 0) * CSTR;  // wave-uniform base
  const float* c1p = pfc + (size_t)(b0 + bg + 1) * CSTR;
  float a00 = 0.f, a01 = 0.f, a02 = 0.f, a10 = 0.f, a11 = 0.f, a12 = 0.f;
#pragma unroll 4
  for (int r = r0; r < r1; ++r) {
    float4 d = D4v[(size_t)r * NJKP + jkg];
    float c0 = c0p[r];               // s_load (uniform)
    float c1 = c1p[r];
    a00 += c0 * d.x; a01 += c0 * d.y; a02 += c0 * d.z;
    a10 += c1 * d.x; a11 += c1 * d.y; a12 += c1 * d.z;
  }
  if (jkg < NJK) {
    float* base = Spart + (size_t)blockIdx.z * SSTRIDE;
    float* o0 = base + ((size_t)(b0 + bg + 0) * 3) * NJK + jkg;
    float* o1 = base + ((size_t)(b0 + bg + 1) * 3) * NJK + jkg;
    o0[0 * NJK] = a00; o0[1 * NJK] = a01; o0[2 * NJK] = a02;
    o1[0 * NJK] = a10; o1[1 * NJK] = a11; o1[2 * NJK] = a12;
  }
}

// ============ k_final3: LDS-staged epilogue; 2 batches/block, all-coalesced ============
__global__ void __launch_bounds__(128) k_final3(const float* __restrict__ Spart,
                                                const float* __restrict__ D4,
                                                const float* __restrict__ A,
                                                float* __restrict__ out) {
  __shared__ float S_ls[2 * 3 * NJK];   // 10.9KB
  __shared__ float A_ls[2 * 288];       // 2.3KB
  __shared__ float c0_ls[NJK];          // 1.8KB
  int blk = blockIdx.x, tid = threadIdx.x;
  int b0 = blk * 2;
  size_t sbase = (size_t)(b0 * 3) * NJK;
  for (int i = tid; i < 2 * 3 * NJK; i += 128)
    S_ls[i] = Spart[sbase + i] + Spart[SSTRIDE + sbase + i];
  for (int i = tid; i < 2 * 288; i += 128)
    A_ls[i] = A[(size_t)b0 * 288 + i];
  for (int i = tid; i < NJK; i += 128)
    c0_ls[i] = D4[((size_t)NCOEF * NJKP + i) * 4];
  __syncthreads();
  if (tid >= 2 * NJO * 3) return;
  int bq = tid / 57, r = tid - bq * 57;
  int j = r / 3, c = r - j * 3;
  const float* S0 = S_ls + (bq * 3 + 0) * NJK + j * NJNT;
  const float* S1 = S_ls + (bq * 3 + 1) * NJK + j * NJNT;
  const float* S2 = S_ls + (bq * 3 + 2) * NJK + j * NJNT;
  const float* Ab = A_ls + bq * 288;
  const float* cc = c0_ls + j * NJNT;
  float acc = 0.f;
#pragma unroll 4
  for (int k = 0; k < NJNT; ++k) {
    const float* Ar = Ab + k * 12 + c * 4;
    acc += Ar[0] * S0[k] + Ar[1] * S1[k] + Ar[2] * S2[k] + Ar[3] * cc[k];
  }
  out[(size_t)(b0 + bq) * 57 + r] = acc;
}

extern "C" void kernel_launch(void* const* d_in, const int* in_sizes, int n_in,
                              void* d_out, int out_size, void* d_ws, size_t ws_size,
                              hipStream_t stream) {
  const float* beta  = (const float*)d_in[0];
  const float* theta = (const float*)d_in[1];
  const float* vtmpl = (const float*)d_in[2];
  const float* sdirs = (const float*)d_in[3];
  const float* Jreg  = (const float*)d_in[4];
  const float* pdirs = (const float*)d_in[5];
  const float* lbs   = (const float*)d_in[6];
  const float* jreg2 = (const float*)d_in[7];
  float* out = (float*)d_out;

  float* ws    = (float*)d_ws;
  short* Cb    = (short*)ws;                              // 512*6912 bf16
  short* Pb    = Cb + (size_t)NJKP * KPAD;                // 768*6912 bf16
  float* Dpart = (float*)(Pb + (size_t)PROWSP * KPAD);    // 12*768*512 f32
  float* D4    = Dpart + (size_t)KSPLIT * PROWSP * NJKP;  // 219*512*4
  float* Spart = D4    + (size_t)D4R * NJKP * 4;          // 2*512*3*456
  float* pfc   = Spart + (size_t)RSP * SSTRIDE;           // 512*224
  float* Rs    = pfc   + (size_t)NBATCH * CSTR;           // 512*216
  float* A     = Rs    + (size_t)NBATCH * 216;            // 512*288
  float* jrT   = A     + (size_t)NBATCH * 288;            // 19*6912 (padded)
  float* wT    = jrT   + (size_t)NJO * CSTRV;             // 24*6912 (padded)
  float* SJ    = wT    + (size_t)NJNT * CSTRV;            // 11*72

  kA<<<dim3(TR2 + RODB + SJB + PMV + PMP), 256, 0, stream>>>(
      jreg2, lbs, Jreg, sdirs, vtmpl, theta, beta, pdirs,
      jrT, wT, SJ, Rs, pfc, Pb);
  kB<<<dim3(CHB + CMB), 256, 0, stream>>>(beta, SJ, Rs, jrT, wT, A, Cb);
  k_gemm<<<dim3(PROWSP / 128, NJKP / 64, KSPLIT), 256, 0, stream>>>(Pb, Cb, Dpart);
  k_redD4<<<dim3((D4R * NJKP + 255) / 256), 256, 0, stream>>>(Dpart, D4);
  k_S5b<<<dim3(NJKP / 64, NBATCH / 8, RSP), 256, 0, stream>>>(D4, pfc, Spart);
  k_final3<<<dim3(NBATCH / 2), 128, 0, stream>>>(Spart, D4, A, out);
}